// Round 6
// baseline (189.615 us; speedup 1.0000x reference)
//
#include <hip/hip_runtime.h>
#include <math.h>

// Problem constants (from setup_inputs): B=16, C=64, H=80, W=80, N=32
constexpr int B = 16, C = 64, H = 80, Wd = 80, N = 32;
constexpr int HW = H * Wd;          // 6400
constexpr int CHW = C * HW;         // 409600
constexpr long long TOTAL = (long long)B * CHW;  // 6,553,600

// Argmax split: 5 chunks of 1280 positions per (b,g)
constexpr int NCHUNK = 5;
constexpr int CHUNK_ELEMS = HW / NCHUNK;   // 1280
constexpr int A_DEPTH = CHUNK_ELEMS / 256; // 5 float4 per thread (no spill)
constexpr int NBLK_A = B * N * NCHUNK;     // 2560 assign-chunk blocks

// Dense tiles
constexpr int K2_PER_THREAD = 16;
constexpr int K2_BLOCK_ELEMS = 256 * K2_PER_THREAD;          // 4096
constexpr int K2_BLOCKS_PER_BATCH = CHW / K2_BLOCK_ELEMS;    // 100
constexpr int NBLK_D = B * K2_BLOCKS_PER_BATCH;              // 1600

// K2 (corrections): 4 gts per block (one per wave), all in same batch
constexpr int NBLK_C = B * N / 4;   // 128

// Workspace layout:
//   [0,     20480) : int2  amax[2560]   {bits(best_giou), idx}
//   [24576, 30976) : float focalp[1600]
//   [32768, 34816) : float4 posp[128]   {l1, giou, focal_corr, npos}
//   [40960, 40964) : int   done
#define WS_FOCALP 24576
#define WS_POSP   32768
#define WS_DONE   40960

// ---------------------------------------------------------------------------
// K1: fused assign-chunk (blocks < 2560) and dense-focal (blocks >= 2560).
// The two streams are independent -> run concurrently in one dispatch.
// GIoU math: contract(off) + exact numpy op order -> bitwise-identical values,
// so argmax with first-index tie-break matches the reference.
// ---------------------------------------------------------------------------
__global__ __launch_bounds__(256) void fused_k1(
    const float* __restrict__ pred,   // [B,C,H,W,4]
    const float* __restrict__ conf,   // [B,C,H,W]
    const float* __restrict__ gtb,    // [B,N,4]
    const int*   __restrict__ gtl,    // [B,N]
    int2*  __restrict__ amax,         // [2560]
    float* __restrict__ focalp,       // [1600]
    int*   __restrict__ done)
{
    const int tid = threadIdx.x;

    if (blockIdx.x == 0 && tid == 0) *done = 0;   // K1 completes before K2 runs

    if (blockIdx.x < NBLK_A) {
        // ---------------- assign-chunk path ----------------
#pragma clang fp contract(off)
        const int blk = blockIdx.x;
        const int bg = blk / NCHUNK;          // 0..511
        const int chunk = blk - bg * NCHUNK;  // 0..4
        const int b = bg >> 5;

        const int lab = gtl[bg];
        const float4 gb = ((const float4*)gtb)[bg];
        const float a2 = (gb.z - gb.x) * (gb.w - gb.y);

        const float4* pc = (const float4*)(pred + (size_t)(b * C + lab) * HW * 4)
                           + chunk * CHUNK_ELEMS;

        float4 buf[A_DEPTH];
#pragma unroll
        for (int k = 0; k < A_DEPTH; k++)
            buf[k] = pc[tid + k * 256];

        float best = -INFINITY;
        int bidx = 0x7fffffff;
#pragma unroll
        for (int k = 0; k < A_DEPTH; k++) {
            float4 pb = buf[k];
            float a1 = (pb.z - pb.x) * (pb.w - pb.y);
            float ltx = fmaxf(pb.x, gb.x), lty = fmaxf(pb.y, gb.y);
            float rbx = fminf(pb.z, gb.z), rby = fminf(pb.w, gb.w);
            float wx = fmaxf(rbx - ltx, 0.0f), wy = fmaxf(rby - lty, 0.0f);
            float inter = wx * wy;
            float uni = (a1 + a2) - inter;
            float iou = inter / uni;
            float lex = fminf(pb.x, gb.x), ley = fminf(pb.y, gb.y);
            float rex = fmaxf(pb.z, gb.z), rey = fmaxf(pb.w, gb.w);
            float ex = fmaxf(rex - lex, 0.0f), ey = fmaxf(rey - ley, 0.0f);
            float ae = ex * ey;
            float gi = iou - (ae - uni) / ae;
            if (gi > best) { best = gi; bidx = chunk * CHUNK_ELEMS + tid + k * 256; }
        }

#pragma unroll
        for (int off = 32; off > 0; off >>= 1) {
            float ov = __shfl_down(best, off, 64);
            int   oi = __shfl_down(bidx, off, 64);
            if (ov > best || (ov == best && oi < bidx)) { best = ov; bidx = oi; }
        }
        __shared__ float sv[4];
        __shared__ int   si[4];
        if ((tid & 63) == 0) { sv[tid >> 6] = best; si[tid >> 6] = bidx; }
        __syncthreads();
        if (tid == 0) {
            float bv = sv[0]; int bi = si[0];
#pragma unroll
            for (int wv = 1; wv < 4; wv++) {
                if (sv[wv] > bv || (sv[wv] == bv && si[wv] < bi)) {
                    bv = sv[wv]; bi = si[wv];
                }
            }
            amax[blk] = make_int2(__float_as_int(bv), bi);
        }
    } else {
        // ---------------- dense focal path (branchless, negatives-only) ----
        const int d = blockIdx.x - NBLK_A;
        const int b = d / K2_BLOCKS_PER_BATCH;
        const int base = (d % K2_BLOCKS_PER_BATCH) * K2_BLOCK_ELEMS;
        const int pos0 = base + tid * K2_PER_THREAD;

        const float4* conf4 = (const float4*)(conf + (size_t)b * CHW);
        float4 q[4];
#pragma unroll
        for (int k = 0; k < 4; k++) q[k] = conf4[(pos0 >> 2) + k];

        float l_f = 0.0f;
#pragma unroll
        for (int k = 0; k < 4; k++) {
            float pv[4] = {q[k].x, q[k].y, q[k].z, q[k].w};
#pragma unroll
            for (int e = 0; e < 4; e++) {
                float p = fminf(fmaxf(pv[e], 1e-6f), 1.0f - 1e-6f);
                l_f += 0.75f * p * p * (-__logf(1.0f - p));
            }
        }

#pragma unroll
        for (int off = 32; off > 0; off >>= 1)
            l_f += __shfl_down(l_f, off, 64);
        __shared__ float swf[4];
        if ((tid & 63) == 0) swf[tid >> 6] = l_f;
        __syncthreads();
        if (tid == 0)
            focalp[d] = swf[0] + swf[1] + swf[2] + swf[3];
    }
}

// ---------------------------------------------------------------------------
// K2: positive corrections per gt (one wave per gt; 4 gts/block, same batch)
// + last-block final reduce. Reproduces matched = max-covering-g via dedup:
// position counted under g iff no valid later gt with same label also covers.
// ---------------------------------------------------------------------------
__global__ __launch_bounds__(256) void fused_k2(
    const float* __restrict__ pred,
    const float* __restrict__ conf,
    const float* __restrict__ gtb,
    const int*   __restrict__ gtl,
    const int2*  __restrict__ amax,
    const float* __restrict__ focalp,
    float4* __restrict__ posp,
    int*    __restrict__ done,
    float*  __restrict__ out)
{
    const int tid = threadIdx.x;
    const int b = (blockIdx.x * 4) >> 5;          // all 4 waves share batch b

    __shared__ int2   s_amax[N * NCHUNK];   // this batch's chunk partials
    __shared__ int4   s_fin[N];             // {valid, mi, mj, lab}
    __shared__ float4 s_gtb[N];

    if (tid < N * NCHUNK) s_amax[tid] = amax[b * N * NCHUNK + tid];
    if (tid < N) s_gtb[tid] = ((const float4*)gtb)[b * N + tid];
    __syncthreads();

    if (tid < N) {
        float best = -INFINITY;
        int idx = 0x7fffffff;
#pragma unroll
        for (int kc = 0; kc < NCHUNK; kc++) {
            int2 pr = s_amax[tid * NCHUNK + kc];
            float v = __int_as_float(pr.x);
            if (v > best || (v == best && pr.y < idx)) { best = v; idx = pr.y; }
        }
        int lab = gtl[b * N + tid];
        s_fin[tid] = make_int4(best > 0.3f ? 1 : 0, idx / Wd, idx % Wd, lab);
    }
    __syncthreads();

    const int g = (blockIdx.x * 4 + (tid >> 6)) & 31;   // this wave's gt
    const int lane = tid & 63;

    float l_l1 = 0.0f, l_gi = 0.0f, l_fc = 0.0f, l_np = 0.0f;
    int4 fin = s_fin[g];
    if (fin.x && lane < 16) {
        const int mi = fin.y, mj = fin.z, lab = fin.w;
        const int r  = mi - 2 + (lane >> 2);
        const int cc = mj - 2 + (lane & 3);
        if (r >= 0 && r < H && cc >= 0 && cc < Wd) {
            // dedup: skip if a later valid gt with same label also covers (r,cc)
            bool mine = true;
            for (int gp = g + 1; gp < N; gp++) {
                int4 f2 = s_fin[gp];
                if (f2.x && f2.w == lab &&
                    r >= f2.y - 2 && r <= f2.y + 1 &&
                    cc >= f2.z - 2 && cc <= f2.z + 1) { mine = false; break; }
            }
            if (mine) {
#pragma clang fp contract(off)
                const size_t pos = (size_t)b * CHW + (size_t)lab * HW + r * Wd + cc;
                float p = conf[pos];
                p = fminf(fmaxf(p, 1e-6f), 1.0f - 1e-6f);
                float om = 1.0f - p;
                l_fc = 0.25f * om * om * (-__logf(p))
                     - 0.75f * p * p * (-__logf(1.0f - p));
                l_np = 1.0f;

                float4 pb = *(const float4*)(pred + pos * 4);
                float4 gbx = s_gtb[g];
                l_l1 = 0.25f * (fabsf(pb.x - gbx.x) + fabsf(pb.y - gbx.y) +
                                fabsf(pb.z - gbx.z) + fabsf(pb.w - gbx.w));

                float a1 = (pb.z - pb.x) * (pb.w - pb.y);
                float a2 = (gbx.z - gbx.x) * (gbx.w - gbx.y);
                float ltx = fmaxf(pb.x, gbx.x), lty = fmaxf(pb.y, gbx.y);
                float rbx = fminf(pb.z, gbx.z), rby = fminf(pb.w, gbx.w);
                float wx = fmaxf(rbx - ltx, 0.0f), wy = fmaxf(rby - lty, 0.0f);
                float inter = wx * wy;
                float uni = (a1 + a2) - inter;
                float iou = inter / uni;
                float lex = fminf(pb.x, gbx.x), ley = fminf(pb.y, gbx.y);
                float rex = fmaxf(pb.z, gbx.z), rey = fmaxf(pb.w, gbx.w);
                float ex = fmaxf(rex - lex, 0.0f), ey = fmaxf(rey - ley, 0.0f);
                float ae = ex * ey;
                float gi = iou - (ae - uni) / ae;
                l_gi = 1.0f - gi;
            }
        }
    }

    // block reduce the 4 sums
#pragma unroll
    for (int off = 32; off > 0; off >>= 1) {
        l_l1 += __shfl_down(l_l1, off, 64);
        l_gi += __shfl_down(l_gi, off, 64);
        l_fc += __shfl_down(l_fc, off, 64);
        l_np += __shfl_down(l_np, off, 64);
    }
    __shared__ float4 swv[4];
    if ((tid & 63) == 0) swv[tid >> 6] = make_float4(l_l1, l_gi, l_fc, l_np);
    __syncthreads();

    __shared__ bool s_last;
    if (tid == 0) {
        float4 s = swv[0];
#pragma unroll
        for (int wv = 1; wv < 4; wv++) {
            s.x += swv[wv].x; s.y += swv[wv].y;
            s.z += swv[wv].z; s.w += swv[wv].w;
        }
        posp[blockIdx.x] = s;
        __threadfence();                       // publish partial device-wide
        int prev = atomicAdd(done, 1);
        s_last = (prev == NBLK_C - 1);
    }
    __syncthreads();

    if (s_last) {
        __threadfence();                       // acquire: see all partials
        float s0 = 0.0f, s1 = 0.0f, s2 = 0.0f, s3 = 0.0f;
        for (int i = tid; i < NBLK_D; i += 256)
            s2 += focalp[i];
        if (tid < NBLK_C) {
            float4 p = posp[tid];
            s0 += p.x; s1 += p.y; s2 += p.z; s3 += p.w;
        }
#pragma unroll
        for (int off = 32; off > 0; off >>= 1) {
            s0 += __shfl_down(s0, off, 64);
            s1 += __shfl_down(s1, off, 64);
            s2 += __shfl_down(s2, off, 64);
            s3 += __shfl_down(s3, off, 64);
        }
        __shared__ float4 fwv[4];
        if ((tid & 63) == 0) fwv[tid >> 6] = make_float4(s0, s1, s2, s3);
        __syncthreads();
        if (tid == 0) {
            float4 s = fwv[0];
#pragma unroll
            for (int wv = 1; wv < 4; wv++) {
                s.x += fwv[wv].x; s.y += fwv[wv].y;
                s.z += fwv[wv].z; s.w += fwv[wv].w;
            }
            float np = s.w;
            float denom = fmaxf(np, 1.0f);
            float l1 = s.x / denom;
            float gi = s.y / denom;
            float cf = s.z / (float)TOTAL;
            out[0] = l1;
            out[1] = gi;
            out[2] = cf;
            out[3] = l1 + 2.0f * gi + cf;
            out[4] = np / (float)TOTAL;
        }
    }
}

extern "C" void kernel_launch(void* const* d_in, const int* in_sizes, int n_in,
                              void* d_out, int out_size, void* d_ws, size_t ws_size,
                              hipStream_t stream) {
    const float* pred = (const float*)d_in[0];  // [B,C,H,W,4]
    const float* conf = (const float*)d_in[1];  // [B,C,H,W]
    // d_in[2] = cam: unused by the loss
    const float* gtb  = (const float*)d_in[3];  // [B,N,4]
    const int*   gtl  = (const int*)d_in[4];    // [B,N]

    int2*   amax   = (int2*)d_ws;
    float*  focalp = (float*)((char*)d_ws + WS_FOCALP);
    float4* posp   = (float4*)((char*)d_ws + WS_POSP);
    int*    done   = (int*)((char*)d_ws + WS_DONE);
    float*  out    = (float*)d_out;

    fused_k1<<<NBLK_A + NBLK_D, 256, 0, stream>>>(pred, conf, gtb, gtl,
                                                  amax, focalp, done);
    fused_k2<<<NBLK_C, 256, 0, stream>>>(pred, conf, gtb, gtl, amax,
                                         focalp, posp, done, out);
}